// Round 1
// baseline (1443.106 us; speedup 1.0000x reference)
//
#include <hip/hip_runtime.h>
#include <math.h>

#define N_PTS 120000
#define D 256
#define BATCH 2
#define NH 8
#define DH 32
#define OUTC 20

#define Zd 60
#define Yd 45
#define Xd 4
#define Gq 10800
#define Sq 21600

#define Ze 12
#define Ye 24
#define Xe 2
#define Gk 576
#define Sk 1152

#define ROWS 16
#define TK 192

// ---- monotonic float<->uint mapping for atomic max ----
__device__ inline unsigned enc_f(float x) {
    unsigned u = __float_as_uint(x);
    return (u & 0x80000000u) ? ~u : (u | 0x80000000u);
}
__device__ inline float dec_f(unsigned m) {
    return (m & 0x80000000u) ? __uint_as_float(m & 0x7fffffffu)
                             : __uint_as_float(~m);
}
// enc_f(x)==0 only for a NaN pattern we never produce, so 0 == "empty".

// ---- kernel 1: pf = X@Wp+bp, ef = X@We+be, scatter-max into segment grids ----
__global__ __launch_bounds__(256) void k_dual_linear_scatter(
    const float* __restrict__ feat,
    const float* __restrict__ Wp, const float* __restrict__ bp,
    const float* __restrict__ We, const float* __restrict__ be,
    const int*  __restrict__ indices,
    unsigned* __restrict__ poolbits, unsigned* __restrict__ embbits)
{
    __shared__ float lf[ROWS][D];
    __shared__ int sq[ROWS], sk[ROWS];
    const int t = threadIdx.x;
    const int row0 = blockIdx.x * ROWS;

    #pragma unroll
    for (int r = 0; r < ROWS; ++r)
        lf[r][t] = feat[(size_t)(row0 + r) * D + t];
    if (t < ROWS) {
        const int* id = indices + (size_t)(row0 + t) * 4;
        int b = id[0], z = id[1], y = id[2], x = id[3];
        sq[t] = ((b * Zd + (z >> 3)) * Yd + (y >> 3)) * Xd + (x >> 3);
        sk[t] = ((b * Ze + (z / 40)) * Ye + (y / 15)) * Xe + (x >> 4);
    }
    __syncthreads();

    float ap[ROWS], ae[ROWS];
    const float bpv = bp[t], bev = be[t];
    #pragma unroll
    for (int r = 0; r < ROWS; ++r) { ap[r] = bpv; ae[r] = bev; }

    for (int k = 0; k < D; k += 4) {
        float wp0 = Wp[(k + 0) * D + t], wp1 = Wp[(k + 1) * D + t];
        float wp2 = Wp[(k + 2) * D + t], wp3 = Wp[(k + 3) * D + t];
        float we0 = We[(k + 0) * D + t], we1 = We[(k + 1) * D + t];
        float we2 = We[(k + 2) * D + t], we3 = We[(k + 3) * D + t];
        #pragma unroll
        for (int r = 0; r < ROWS; ++r) {
            float4 f = *(const float4*)&lf[r][k];
            ap[r] += f.x * wp0 + f.y * wp1 + f.z * wp2 + f.w * wp3;
            ae[r] += f.x * we0 + f.y * we1 + f.z * we2 + f.w * we3;
        }
    }

    #pragma unroll
    for (int r = 0; r < ROWS; ++r) {
        atomicMax(&poolbits[(size_t)sq[r] * D + t], enc_f(ap[r]));
        atomicMax(&embbits [(size_t)sk[r] * D + t], enc_f(ae[r]));
    }
}

// ---- sine PE helper: channel j given original-unit coords ----
__device__ inline float pe_val(int j, float cz, float cy, float cx) {
    if (j >= 252) return 0.f;
    int dim = j / 84;
    int f = j % 84;
    int fi = (f >= 42) ? (f - 42) : f;
    float c  = (dim == 0) ? cz : ((dim == 1) ? cy : cx);
    float sp = (dim == 0) ? 480.f : ((dim == 1) ? 360.f : 32.f);
    float cn = c / sp * 6.28318530717958647692f;
    // t = 10000^(fi/42)
    float tt = expf((float)fi * (9.210340371976184f / 42.f));
    float ang = cn / tt;
    return (f >= 42) ? cosf(ang) : sinf(ang);
}

// ---- kernel 2a: pool_max (decode, empty->0) + PE -> pool_feat ----
__global__ __launch_bounds__(256) void k_pe_pool(
    const unsigned* __restrict__ bits, float* __restrict__ out)
{
    int s = blockIdx.x, j = threadIdx.x;
    unsigned m = bits[(size_t)s * D + j];
    float v = m ? dec_f(m) : 0.f;
    int rem = s % Gq;
    float cz = (float)((rem / (Yd * Xd)) * 8);
    float cy = (float)(((rem / Xd) % Yd) * 8);
    float cx = (float)((rem % Xd) * 8);
    out[(size_t)s * D + j] = v + pe_val(j, cz, cy, cx);
}

// ---- kernel 2b: emb_max + PE -> emb_feat, plus kmask ----
__global__ __launch_bounds__(256) void k_pe_emb(
    const unsigned* __restrict__ bits, float* __restrict__ out,
    int* __restrict__ kmask)
{
    int s = blockIdx.x, j = threadIdx.x;
    unsigned m = bits[(size_t)s * D + j];
    float v = m ? dec_f(m) : 0.f;
    int rem = s % Gk;
    float cz = (float)((rem / (Ye * Xe)) * 40);
    float cy = (float)(((rem / Xe) % Ye) * 15);
    float cx = (float)((rem % Xe) * 16);
    out[(size_t)s * D + j] = v + pe_val(j, cz, cy, cx);
    if (j == 0) kmask[s] = (bits[(size_t)s * D] != 0u) ? 1 : 0;
}

// ---- generic [M,256] @ [256,256] + bias ----
__global__ __launch_bounds__(256) void k_linear(
    const float* __restrict__ in, const float* __restrict__ W,
    const float* __restrict__ bias, float* __restrict__ out)
{
    __shared__ float lf[ROWS][D];
    const int t = threadIdx.x;
    const int row0 = blockIdx.x * ROWS;
    #pragma unroll
    for (int r = 0; r < ROWS; ++r)
        lf[r][t] = in[(size_t)(row0 + r) * D + t];
    __syncthreads();

    float acc[ROWS];
    const float bv = bias[t];
    #pragma unroll
    for (int r = 0; r < ROWS; ++r) acc[r] = bv;

    for (int k = 0; k < D; k += 4) {
        float w0 = W[(k + 0) * D + t], w1 = W[(k + 1) * D + t];
        float w2 = W[(k + 2) * D + t], w3 = W[(k + 3) * D + t];
        #pragma unroll
        for (int r = 0; r < ROWS; ++r) {
            float4 f = *(const float4*)&lf[r][k];
            acc[r] += f.x * w0 + f.y * w1 + f.z * w2 + f.w * w3;
        }
    }
    #pragma unroll
    for (int r = 0; r < ROWS; ++r)
        out[(size_t)(row0 + r) * D + t] = acc[r];
}

// ---- attention: one thread = one query row for one head; online softmax ----
__global__ __launch_bounds__(256) void k_attn(
    const float* __restrict__ Q, const float* __restrict__ Kg,
    const float* __restrict__ Vg, const int* __restrict__ kmask,
    float* __restrict__ O)
{
    __shared__ float Kl[TK][DH];
    __shared__ float Vl[TK][DH];
    __shared__ int ml[TK];

    const int bh = blockIdx.y;
    const int b = bh / NH, h = bh % NH;
    const int qi = blockIdx.x * 256 + threadIdx.x;
    const bool active = (qi < Gq);

    float q[DH], acc[DH];
    float m = -3.0e38f, l = 0.f;
    if (active) {
        const float4* qp = (const float4*)(Q + ((size_t)(b * Gq + qi)) * D + h * DH);
        #pragma unroll
        for (int d4 = 0; d4 < DH / 4; ++d4) {
            float4 f = qp[d4];
            q[4 * d4 + 0] = f.x; q[4 * d4 + 1] = f.y;
            q[4 * d4 + 2] = f.z; q[4 * d4 + 3] = f.w;
        }
    } else {
        #pragma unroll
        for (int d = 0; d < DH; ++d) q[d] = 0.f;
    }
    #pragma unroll
    for (int d = 0; d < DH; ++d) acc[d] = 0.f;

    for (int k0 = 0; k0 < Gk; k0 += TK) {
        __syncthreads();
        for (int idx = threadIdx.x; idx < TK * DH; idx += 256) {
            int kk = idx / DH, d = idx % DH;
            size_t g = ((size_t)(b * Gk + k0 + kk)) * D + h * DH + d;
            Kl[kk][d] = Kg[g];
            Vl[kk][d] = Vg[g];
        }
        for (int idx = threadIdx.x; idx < TK; idx += 256)
            ml[idx] = kmask[b * Gk + k0 + idx];
        __syncthreads();

        if (active) {
            for (int kk = 0; kk < TK; ++kk) {
                if (!ml[kk]) continue;
                float s = 0.f;
                #pragma unroll
                for (int d = 0; d < DH; ++d) s += q[d] * Kl[kk][d];
                s *= 0.17677669529663688f; // 1/sqrt(32)
                if (s > m) {
                    float f = __expf(m - s);
                    l *= f;
                    #pragma unroll
                    for (int d = 0; d < DH; ++d) acc[d] *= f;
                    m = s;
                }
                float p = __expf(s - m);
                l += p;
                #pragma unroll
                for (int d = 0; d < DH; ++d) acc[d] += p * Vl[kk][d];
            }
        }
    }

    if (active) {
        float inv = (l > 0.f) ? (1.f / l) : 0.f;
        float* op = O + ((size_t)(b * Gq + qi)) * D + h * DH;
        #pragma unroll
        for (int d = 0; d < DH; ++d) op[d] = acc[d] * inv;
    }
}

// ---- residual + LayerNorm ----
__global__ __launch_bounds__(256) void k_ln(
    const float* __restrict__ oproj, const float* __restrict__ resid,
    const float* __restrict__ g, const float* __restrict__ bta,
    float* __restrict__ out)
{
    const int s = blockIdx.x, t = threadIdx.x;
    float h = resid[(size_t)s * D + t] + oproj[(size_t)s * D + t];

    float s1 = h, s2 = h * h;
    for (int o = 32; o > 0; o >>= 1) {
        s1 += __shfl_down(s1, o);
        s2 += __shfl_down(s2, o);
    }
    __shared__ float r1[4], r2[4];
    __shared__ float mu_s, rstd_s;
    int w = t >> 6;
    if ((t & 63) == 0) { r1[w] = s1; r2[w] = s2; }
    __syncthreads();
    if (t == 0) {
        float a = r1[0] + r1[1] + r1[2] + r1[3];
        float bsum = r2[0] + r2[1] + r2[2] + r2[3];
        float mu = a * (1.f / 256.f);
        float var = bsum * (1.f / 256.f) - mu * mu;
        mu_s = mu;
        rstd_s = rsqrtf(var + 1e-5f);
    }
    __syncthreads();
    out[(size_t)s * D + t] = (h - mu_s) * rstd_s * g[t] + bta[t];
}

// ---- final: vox = feat + mhca[seg_q], logits = vox @ W_seg + b_seg ----
#define PTS 16
__global__ __launch_bounds__(320) void k_logits(
    const float* __restrict__ feat, const float* __restrict__ mhca,
    const int* __restrict__ indices, const float* __restrict__ Wseg,
    const float* __restrict__ bseg, float* __restrict__ out)
{
    __shared__ float vox[PTS][D + 1];
    __shared__ float Wl[D * OUTC];
    __shared__ int sq[PTS];
    const int t = threadIdx.x;
    const int p0 = blockIdx.x * PTS;

    if (t < PTS) {
        const int* id = indices + (size_t)(p0 + t) * 4;
        sq[t] = ((id[0] * Zd + (id[1] >> 3)) * Yd + (id[2] >> 3)) * Xd + (id[3] >> 3);
    }
    for (int idx = t; idx < D * OUTC; idx += 320) Wl[idx] = Wseg[idx];
    __syncthreads();
    for (int idx = t; idx < PTS * D; idx += 320) {
        int r = idx / D, k = idx % D;
        vox[r][k] = feat[(size_t)(p0 + r) * D + k] + mhca[(size_t)sq[r] * D + k];
    }
    __syncthreads();

    const int r = t / OUTC, o = t % OUTC;
    float acc = bseg[o];
    #pragma unroll 4
    for (int k = 0; k < D; ++k) acc += vox[r][k] * Wl[k * OUTC + o];
    out[(size_t)(p0 + r) * OUTC + o] = acc;
}

extern "C" void kernel_launch(void* const* d_in, const int* in_sizes, int n_in,
                              void* d_out, int out_size, void* d_ws, size_t ws_size,
                              hipStream_t stream) {
    const float* features = (const float*)d_in[0];
    const float* W_pool = (const float*)d_in[1];
    const float* b_pool = (const float*)d_in[2];
    const float* W_emb  = (const float*)d_in[3];
    const float* b_emb  = (const float*)d_in[4];
    const float* Wq = (const float*)d_in[5];
    const float* bq = (const float*)d_in[6];
    const float* Wk = (const float*)d_in[7];
    const float* bk = (const float*)d_in[8];
    const float* Wv = (const float*)d_in[9];
    const float* bv = (const float*)d_in[10];
    const float* Wo = (const float*)d_in[11];
    const float* bo = (const float*)d_in[12];
    const float* ln_g = (const float*)d_in[13];
    const float* ln_b = (const float*)d_in[14];
    const float* W_seg = (const float*)d_in[15];
    const float* b_seg = (const float*)d_in[16];
    const int* indices = (const int*)d_in[17];
    float* out = (float*)d_out;

    float* ws = (float*)d_ws;
    const size_t SQD = (size_t)Sq * D;   // 5,529,600
    const size_t SKD = (size_t)Sk * D;   // 294,912
    size_t o0 = 0;             // poolbits -> attnO -> mhca
    size_t o1 = o0 + SQD;      // embbits
    size_t o2 = o1 + SKD;      // pool_feat
    size_t o3 = o2 + SQD;      // emb_feat
    size_t o4 = o3 + SKD;      // Q -> oproj
    size_t o5 = o4 + SQD;      // K
    size_t o6 = o5 + SKD;      // V
    size_t o7 = o6 + SKD;      // kmask

    unsigned* poolbits = (unsigned*)(ws + o0);
    unsigned* embbits  = (unsigned*)(ws + o1);
    float* pool_feat = ws + o2;
    float* emb_feat  = ws + o3;
    float* Qb = ws + o4;
    float* Kb = ws + o5;
    float* Vb = ws + o6;
    int* kmask = (int*)(ws + o7);
    float* attnO = ws + o0;
    float* oproj = ws + o4;
    float* mhca  = ws + o0;

    // zero the two scatter-max bit buffers (adjacent at start of ws)
    hipMemsetAsync(d_ws, 0, (SQD + SKD) * sizeof(unsigned), stream);

    k_dual_linear_scatter<<<N_PTS / ROWS, 256, 0, stream>>>(
        features, W_pool, b_pool, W_emb, b_emb, indices, poolbits, embbits);

    k_pe_pool<<<Sq, 256, 0, stream>>>(poolbits, pool_feat);
    k_pe_emb<<<Sk, 256, 0, stream>>>(embbits, emb_feat, kmask);

    k_linear<<<Sq / ROWS, 256, 0, stream>>>(pool_feat, Wq, bq, Qb);
    k_linear<<<Sk / ROWS, 256, 0, stream>>>(emb_feat, Wk, bk, Kb);
    k_linear<<<Sk / ROWS, 256, 0, stream>>>(emb_feat, Wv, bv, Vb);

    dim3 ag((Gq + 255) / 256, BATCH * NH);
    k_attn<<<ag, 256, 0, stream>>>(Qb, Kb, Vb, kmask, attnO);

    k_linear<<<Sq / ROWS, 256, 0, stream>>>(attnO, Wo, bo, oproj);
    k_ln<<<Sq, 256, 0, stream>>>(oproj, pool_feat, ln_g, ln_b, mhca);

    k_logits<<<N_PTS / PTS, 320, 0, stream>>>(
        features, mhca, indices, W_seg, b_seg, out);
}

// Round 4
// 937.416 us; speedup vs baseline: 1.5395x; 1.5395x over previous
//
#include <hip/hip_runtime.h>
#include <math.h>

#define N_PTS 120000
#define D 256
#define BATCH 2
#define NH 8
#define DH 32
#define OUTC 20

#define Zd 60
#define Yd 45
#define Xd 4
#define Gq 10800
#define Sq 21600

#define Ze 12
#define Ye 24
#define Xe 2
#define Gk 576
#define Sk 1152

#define TK 192

typedef __bf16 bf16_t;
typedef __attribute__((ext_vector_type(8))) __bf16 bf16x8;
typedef __attribute__((ext_vector_type(4))) __bf16 bf16x4;
typedef __attribute__((ext_vector_type(4))) float f32x4;

// ---- monotonic float<->uint mapping for atomic max ----
__device__ inline unsigned enc_f(float x) {
    unsigned u = __float_as_uint(x);
    return (u & 0x80000000u) ? ~u : (u | 0x80000000u);
}
__device__ inline float dec_f(unsigned m) {
    return (m & 0x80000000u) ? __uint_as_float(m & 0x7fffffffu)
                             : __uint_as_float(~m);
}

// ---- weight prep: transpose + fp32->bf16; bias concat ----
__global__ __launch_bounds__(256) void k_prep(
    const float* __restrict__ Wp, const float* __restrict__ We,
    const float* __restrict__ Wq, const float* __restrict__ Wk,
    const float* __restrict__ Wv, const float* __restrict__ Wo,
    const float* __restrict__ bp, const float* __restrict__ be,
    const float* __restrict__ bk, const float* __restrict__ bv,
    bf16_t* __restrict__ Wpe, bf16_t* __restrict__ Wqt,
    bf16_t* __restrict__ Wkv, bf16_t* __restrict__ Wot,
    float* __restrict__ bpe, float* __restrict__ bkv)
{
    int n = blockIdx.x, k = threadIdx.x;
    if (n < 512) {
        const float* S = (n < 256) ? Wp : We;
        int nn = n & 255;
        Wpe[n * 256 + k] = (bf16_t)S[k * 256 + nn];
    } else if (n < 768) {
        int nn = n - 512;
        Wqt[nn * 256 + k] = (bf16_t)Wq[k * 256 + nn];
    } else if (n < 1280) {
        int m2 = n - 768;
        const float* S = (m2 < 256) ? Wk : Wv;
        int nn = m2 & 255;
        Wkv[m2 * 256 + k] = (bf16_t)S[k * 256 + nn];
    } else if (n < 1536) {
        int nn = n - 1280;
        Wot[nn * 256 + k] = (bf16_t)Wo[k * 256 + nn];
    } else {
        bpe[k] = bp[k]; bpe[256 + k] = be[k];
        bkv[k] = bk[k]; bkv[256 + k] = bv[k];
    }
}

// ---- MFMA GEMM: [M x 256] (fp32, converted on stage) @ Wt[N x 256] bf16 ----
// block: 512 thr (8 waves, 2x4), BM=128 BN=256 BK=64; wave tile 64x64.
// mode 0: out[grow*ldo + col] = acc + bias[gcol]
// mode 1: scatter-max: ntile0 -> poolbits via seg_q, ntile1 -> embbits via seg_k
__global__ __launch_bounds__(512, 2) void k_gemm(
    const float* __restrict__ A, int M,
    const bf16_t* __restrict__ Wt, const float* __restrict__ bias,
    int mode, float* __restrict__ outp, int ldo,
    const int* __restrict__ indices,
    unsigned* __restrict__ poolbits, unsigned* __restrict__ embbits)
{
    __shared__ __align__(16) bf16_t Abuf[128][72];
    __shared__ __align__(16) bf16_t Bbuf[256][72];
    __shared__ int sq_s[128], sk_s[128];

    const int t = threadIdx.x;
    const int wave = t >> 6, lane = t & 63;
    const int wr = wave >> 2, wc = wave & 3;
    const int lrow = lane & 15, quad = lane >> 4;
    const int row0 = blockIdx.y * 128;
    const int ntile = blockIdx.x;

    if (mode == 1 && t < 128) {
        int row = row0 + t;
        if (row < M) {
            const int* id = indices + (size_t)row * 4;
            int b = id[0], z = id[1], y = id[2], x = id[3];
            sq_s[t] = ((b * Zd + (z >> 3)) * Yd + (y >> 3)) * Xd + (x >> 3);
            sk_s[t] = ((b * Ze + (z / 40)) * Ye + (y / 15)) * Xe + (x >> 4);
        } else { sq_s[t] = 0; sk_s[t] = 0; }
    }

    f32x4 acc[4][4];
    #pragma unroll
    for (int mi = 0; mi < 4; ++mi)
        #pragma unroll
        for (int ni = 0; ni < 4; ++ni)
            acc[mi][ni] = (f32x4){0.f, 0.f, 0.f, 0.f};

    for (int k0 = 0; k0 < 256; k0 += 64) {
        // stage A (fp32 -> bf16): 128 rows x 16 chunks of 4
        #pragma unroll
        for (int i = 0; i < 4; ++i) {
            int c = i * 512 + t;
            int r = c >> 4, c4 = c & 15;
            float4 v = make_float4(0.f, 0.f, 0.f, 0.f);
            if (row0 + r < M)
                v = *(const float4*)(A + (size_t)(row0 + r) * 256 + k0 + c4 * 4);
            bf16x4 bv4;
            bv4[0] = (bf16_t)v.x; bv4[1] = (bf16_t)v.y;
            bv4[2] = (bf16_t)v.z; bv4[3] = (bf16_t)v.w;
            *(bf16x4*)&Abuf[r][c4 * 4] = bv4;
        }
        // stage B (bf16, [n][k]): 256 rows x 8 chunks of 8
        #pragma unroll
        for (int i = 0; i < 4; ++i) {
            int c = i * 512 + t;
            int r = c >> 3, c8 = c & 7;
            uint4 w = *(const uint4*)(Wt + ((size_t)(ntile * 256 + r)) * 256 + k0 + c8 * 8);
            *(uint4*)&Bbuf[r][c8 * 8] = w;
        }
        __syncthreads();

        #pragma unroll
        for (int kk = 0; kk < 64; kk += 32) {
            bf16x8 Af[4], Bf[4];
            #pragma unroll
            for (int mi = 0; mi < 4; ++mi)
                Af[mi] = *(const bf16x8*)&Abuf[wr * 64 + mi * 16 + lrow][kk + quad * 8];
            #pragma unroll
            for (int ni = 0; ni < 4; ++ni)
                Bf[ni] = *(const bf16x8*)&Bbuf[wc * 64 + ni * 16 + lrow][kk + quad * 8];
            #pragma unroll
            for (int mi = 0; mi < 4; ++mi)
                #pragma unroll
                for (int ni = 0; ni < 4; ++ni)
                    acc[mi][ni] = __builtin_amdgcn_mfma_f32_16x16x32_bf16(
                        Af[mi], Bf[ni], acc[mi][ni], 0, 0, 0);
        }
        __syncthreads();
    }

    const int colb = ntile * 256 + wc * 64;
    float biasv[4];
    #pragma unroll
    for (int ni = 0; ni < 4; ++ni) biasv[ni] = bias[colb + ni * 16 + lrow];

    if (mode == 0) {
        #pragma unroll
        for (int mi = 0; mi < 4; ++mi) {
            int lr = wr * 64 + mi * 16 + quad * 4;
            #pragma unroll
            for (int reg = 0; reg < 4; ++reg) {
                int grow = row0 + lr + reg;
                if (grow >= M) continue;
                #pragma unroll
                for (int ni = 0; ni < 4; ++ni) {
                    int col = colb + ni * 16 + lrow;
                    outp[(size_t)grow * ldo + col] = acc[mi][ni][reg] + biasv[ni];
                }
            }
        }
    } else {
        #pragma unroll
        for (int mi = 0; mi < 4; ++mi) {
            int lr = wr * 64 + mi * 16 + quad * 4;
            #pragma unroll
            for (int reg = 0; reg < 4; ++reg) {
                int grow = row0 + lr + reg;
                if (grow >= M) continue;
                #pragma unroll
                for (int ni = 0; ni < 4; ++ni) {
                    int col = colb + ni * 16 + lrow;
                    float v = acc[mi][ni][reg] + biasv[ni];
                    if (col < 256)
                        atomicMax(&poolbits[(size_t)sq_s[lr + reg] * 256 + col], enc_f(v));
                    else
                        atomicMax(&embbits[(size_t)sk_s[lr + reg] * 256 + (col - 256)], enc_f(v));
                }
            }
        }
    }
}

// ---- sine PE helper ----
__device__ inline float pe_val(int j, float cz, float cy, float cx) {
    if (j >= 252) return 0.f;
    int dim = j / 84;
    int f = j % 84;
    int fi = (f >= 42) ? (f - 42) : f;
    float c  = (dim == 0) ? cz : ((dim == 1) ? cy : cx);
    float sp = (dim == 0) ? 480.f : ((dim == 1) ? 360.f : 32.f);
    float cn = c / sp * 6.28318530717958647692f;
    float tt = expf((float)fi * (9.210340371976184f / 42.f));
    float ang = cn / tt;
    return (f >= 42) ? cosf(ang) : sinf(ang);
}

__global__ __launch_bounds__(256) void k_pe_pool(
    const unsigned* __restrict__ bits, float* __restrict__ out)
{
    int s = blockIdx.x, j = threadIdx.x;
    unsigned m = bits[(size_t)s * D + j];
    float v = m ? dec_f(m) : 0.f;
    int rem = s % Gq;
    float cz = (float)((rem / (Yd * Xd)) * 8);
    float cy = (float)(((rem / Xd) % Yd) * 8);
    float cx = (float)((rem % Xd) * 8);
    out[(size_t)s * D + j] = v + pe_val(j, cz, cy, cx);
}

__global__ __launch_bounds__(256) void k_pe_emb(
    const unsigned* __restrict__ bits, float* __restrict__ out,
    int* __restrict__ kmask)
{
    int s = blockIdx.x, j = threadIdx.x;
    unsigned m = bits[(size_t)s * D + j];
    float v = m ? dec_f(m) : 0.f;
    int rem = s % Gk;
    float cz = (float)((rem / (Ye * Xe)) * 40);
    float cy = (float)(((rem / Xe) % Ye) * 15);
    float cx = (float)((rem % Xe) * 16);
    out[(size_t)s * D + j] = v + pe_val(j, cz, cy, cx);
    if (j == 0) kmask[s] = (bits[(size_t)s * D] != 0u) ? 1 : 0;
}

// ---- attention over interleaved KV [Sk][512] (K at +0, V at +256) ----
__global__ __launch_bounds__(256) void k_attn(
    const float* __restrict__ Q, const float* __restrict__ KV,
    const int* __restrict__ kmask, float* __restrict__ O)
{
    __shared__ float Kl[TK][DH];
    __shared__ float Vl[TK][DH];
    __shared__ int ml[TK];

    const int bh = blockIdx.y;
    const int b = bh / NH, h = bh % NH;
    const int qi = blockIdx.x * 256 + threadIdx.x;
    const bool active = (qi < Gq);

    float q[DH], acc[DH];
    float m = -3.0e38f, l = 0.f;
    if (active) {
        const float4* qp = (const float4*)(Q + ((size_t)(b * Gq + qi)) * D + h * DH);
        #pragma unroll
        for (int d4 = 0; d4 < DH / 4; ++d4) {
            float4 f = qp[d4];
            q[4 * d4 + 0] = f.x; q[4 * d4 + 1] = f.y;
            q[4 * d4 + 2] = f.z; q[4 * d4 + 3] = f.w;
        }
    } else {
        #pragma unroll
        for (int d = 0; d < DH; ++d) q[d] = 0.f;
    }
    #pragma unroll
    for (int d = 0; d < DH; ++d) acc[d] = 0.f;

    for (int k0 = 0; k0 < Gk; k0 += TK) {
        __syncthreads();
        for (int idx = threadIdx.x; idx < TK * DH; idx += 256) {
            int kk = idx / DH, d = idx % DH;
            size_t g = ((size_t)(b * Gk + k0 + kk)) * 512 + h * DH + d;
            Kl[kk][d] = KV[g];
            Vl[kk][d] = KV[g + 256];
        }
        for (int idx = threadIdx.x; idx < TK; idx += 256)
            ml[idx] = kmask[b * Gk + k0 + idx];
        __syncthreads();

        if (active) {
            for (int kk = 0; kk < TK; ++kk) {
                if (!ml[kk]) continue;
                float s = 0.f;
                #pragma unroll
                for (int d = 0; d < DH; ++d) s += q[d] * Kl[kk][d];
                s *= 0.17677669529663688f; // 1/sqrt(32)
                if (s > m) {
                    float f = __expf(m - s);
                    l *= f;
                    #pragma unroll
                    for (int d = 0; d < DH; ++d) acc[d] *= f;
                    m = s;
                }
                float p = __expf(s - m);
                l += p;
                #pragma unroll
                for (int d = 0; d < DH; ++d) acc[d] += p * Vl[kk][d];
            }
        }
    }

    if (active) {
        float inv = (l > 0.f) ? (1.f / l) : 0.f;
        float* op = O + ((size_t)(b * Gq + qi)) * D + h * DH;
        #pragma unroll
        for (int d = 0; d < DH; ++d) op[d] = acc[d] * inv;
    }
}

// ---- residual + LayerNorm ----
__global__ __launch_bounds__(256) void k_ln(
    const float* __restrict__ oproj, const float* __restrict__ resid,
    const float* __restrict__ g, const float* __restrict__ bta,
    float* __restrict__ out)
{
    const int s = blockIdx.x, t = threadIdx.x;
    float h = resid[(size_t)s * D + t] + oproj[(size_t)s * D + t];

    float s1 = h, s2 = h * h;
    for (int o = 32; o > 0; o >>= 1) {
        s1 += __shfl_down(s1, o);
        s2 += __shfl_down(s2, o);
    }
    __shared__ float r1[4], r2[4];
    __shared__ float mu_s, rstd_s;
    int w = t >> 6;
    if ((t & 63) == 0) { r1[w] = s1; r2[w] = s2; }
    __syncthreads();
    if (t == 0) {
        float a = r1[0] + r1[1] + r1[2] + r1[3];
        float bsum = r2[0] + r2[1] + r2[2] + r2[3];
        float mu = a * (1.f / 256.f);
        float var = bsum * (1.f / 256.f) - mu * mu;
        mu_s = mu;
        rstd_s = rsqrtf(var + 1e-5f);
    }
    __syncthreads();
    out[(size_t)s * D + t] = (h - mu_s) * rstd_s * g[t] + bta[t];
}

// ---- final: vox = feat + mhca[seg_q], logits = vox @ W_seg + b_seg ----
#define PTS 16
__global__ __launch_bounds__(320) void k_logits(
    const float* __restrict__ feat, const float* __restrict__ mhca,
    const int* __restrict__ indices, const float* __restrict__ Wseg,
    const float* __restrict__ bseg, float* __restrict__ out)
{
    __shared__ float vox[PTS][D + 1];
    __shared__ float Wl[D * OUTC];
    __shared__ int sq[PTS];
    const int t = threadIdx.x;
    const int p0 = blockIdx.x * PTS;

    if (t < PTS) {
        const int* id = indices + (size_t)(p0 + t) * 4;
        sq[t] = ((id[0] * Zd + (id[1] >> 3)) * Yd + (id[2] >> 3)) * Xd + (id[3] >> 3);
    }
    for (int idx = t; idx < D * OUTC; idx += 320) Wl[idx] = Wseg[idx];
    __syncthreads();
    for (int idx = t; idx < PTS * D; idx += 320) {
        int r = idx / D, k = idx % D;
        vox[r][k] = feat[(size_t)(p0 + r) * D + k] + mhca[(size_t)sq[r] * D + k];
    }
    __syncthreads();

    const int r = t / OUTC, o = t % OUTC;
    float acc = bseg[o];
    #pragma unroll 4
    for (int k = 0; k < D; ++k) acc += vox[r][k] * Wl[k * OUTC + o];
    out[(size_t)(p0 + r) * OUTC + o] = acc;
}

extern "C" void kernel_launch(void* const* d_in, const int* in_sizes, int n_in,
                              void* d_out, int out_size, void* d_ws, size_t ws_size,
                              hipStream_t stream) {
    const float* features = (const float*)d_in[0];
    const float* W_pool = (const float*)d_in[1];
    const float* b_pool = (const float*)d_in[2];
    const float* W_emb  = (const float*)d_in[3];
    const float* b_emb  = (const float*)d_in[4];
    const float* Wq = (const float*)d_in[5];
    const float* bq = (const float*)d_in[6];
    const float* Wk = (const float*)d_in[7];
    const float* bk = (const float*)d_in[8];
    const float* Wv = (const float*)d_in[9];
    const float* bv = (const float*)d_in[10];
    const float* Wo = (const float*)d_in[11];
    const float* bo = (const float*)d_in[12];
    const float* ln_g = (const float*)d_in[13];
    const float* ln_b = (const float*)d_in[14];
    const float* W_seg = (const float*)d_in[15];
    const float* b_seg = (const float*)d_in[16];
    const int* indices = (const int*)d_in[17];
    float* out = (float*)d_out;

    float* ws = (float*)d_ws;
    const size_t SQD = (size_t)Sq * D;   // 5,529,600
    const size_t SKD = (size_t)Sk * D;   // 294,912
    // ALL offsets in float (4-byte) units.
    size_t o0 = 0;               // poolbits -> attnO -> mhca
    size_t o1 = o0 + SQD;        // embbits
    size_t o2 = o1 + SKD;        // pool_feat
    size_t o3 = o2 + SQD;        // emb_feat
    size_t o4 = o3 + SKD;        // Q -> oproj
    size_t o5 = o4 + SQD;        // KV (interleaved, [Sk][512])
    size_t o6 = o5 + 2 * SKD;    // kmask (1152 ints)
    size_t o7 = o6 + 2048;       // Wpe bf16 [512][256] = 65536 floats
    size_t o8 = o7 + 65536;      // Wqt bf16 [256][256] = 32768 floats
    size_t o9 = o8 + 32768;      // Wkv bf16 [512][256] = 65536 floats
    size_t o10 = o9 + 65536;     // Wot bf16 [256][256] = 32768 floats
    size_t o11 = o10 + 32768;    // bias pe [512]
    size_t o12 = o11 + 512;      // bias kv [512]

    unsigned* poolbits = (unsigned*)(ws + o0);
    unsigned* embbits  = (unsigned*)(ws + o1);
    float* pool_feat = ws + o2;
    float* emb_feat  = ws + o3;
    float* Qb  = ws + o4;
    float* KVb = ws + o5;
    int* kmask = (int*)(ws + o6);
    bf16_t* Wpe = (bf16_t*)(ws + o7);
    bf16_t* Wqt = (bf16_t*)(ws + o8);
    bf16_t* Wkv = (bf16_t*)(ws + o9);
    bf16_t* Wot = (bf16_t*)(ws + o10);
    float* bpe = ws + o11;
    float* bkv = ws + o12;
    float* attnO = ws + o0;
    float* oproj = ws + o4;
    float* mhca  = ws + o0;

    hipMemsetAsync(d_ws, 0, (SQD + SKD) * sizeof(unsigned), stream);

    k_prep<<<1537, 256, 0, stream>>>(W_pool, W_emb, Wq, Wk, Wv, Wo,
                                     b_pool, b_emb, bk, bv,
                                     Wpe, Wqt, Wkv, Wot, bpe, bkv);

    // dual linear + scatter-max: [120000x256] @ Wpe^T[512x256]
    {
        dim3 g(2, (N_PTS + 127) / 128);
        k_gemm<<<g, 512, 0, stream>>>(features, N_PTS, Wpe, bpe, 1,
                                      nullptr, 0, indices, poolbits, embbits);
    }

    k_pe_pool<<<Sq, 256, 0, stream>>>(poolbits, pool_feat);
    k_pe_emb<<<Sk, 256, 0, stream>>>(embbits, emb_feat, kmask);

    // Q = pool_feat @ Wq + bq
    {
        dim3 g(1, (Sq + 127) / 128);
        k_gemm<<<g, 512, 0, stream>>>(pool_feat, Sq, Wqt, bq, 0,
                                      Qb, 256, nullptr, nullptr, nullptr);
    }
    // KV = emb_feat @ [Wk|Wv] + [bk|bv], interleaved [Sk][512]
    {
        dim3 g(2, (Sk + 127) / 128);
        k_gemm<<<g, 512, 0, stream>>>(emb_feat, Sk, Wkv, bkv, 0,
                                      KVb, 512, nullptr, nullptr, nullptr);
    }

    dim3 ag((Gq + 255) / 256, BATCH * NH);
    k_attn<<<ag, 256, 0, stream>>>(Qb, KVb, kmask, attnO);

    // oproj = attnO @ Wo + bo
    {
        dim3 g(1, (Sq + 127) / 128);
        k_gemm<<<g, 512, 0, stream>>>(attnO, Sq, Wot, bo, 0,
                                      oproj, 256, nullptr, nullptr, nullptr);
    }

    k_ln<<<Sq, 256, 0, stream>>>(oproj, pool_feat, ln_g, ln_b, mhca);

    k_logits<<<N_PTS / PTS, 320, 0, stream>>>(
        features, mhca, indices, W_seg, b_seg, out);
}

// Round 5
// 726.178 us; speedup vs baseline: 1.9873x; 1.2909x over previous
//
#include <hip/hip_runtime.h>
#include <math.h>

#define N_PTS 120000
#define D 256
#define BATCH 2
#define NH 8
#define DH 32
#define OUTC 20

#define Zd 60
#define Yd 45
#define Xd 4
#define Gq 10800
#define Sq 21600

#define Ze 12
#define Ye 24
#define Xe 2
#define Gk 576
#define Sk 1152

typedef __bf16 bf16_t;
typedef __attribute__((ext_vector_type(8))) __bf16 bf16x8;
typedef __attribute__((ext_vector_type(4))) __bf16 bf16x4;
typedef __attribute__((ext_vector_type(4))) float f32x4;

// ---- monotonic float<->uint mapping for atomic max ----
__device__ inline unsigned enc_f(float x) {
    unsigned u = __float_as_uint(x);
    return (u & 0x80000000u) ? ~u : (u | 0x80000000u);
}
__device__ inline float dec_f(unsigned m) {
    return (m & 0x80000000u) ? __uint_as_float(m & 0x7fffffffu)
                             : __uint_as_float(~m);
}

// ---- weight prep: transpose + fp32->bf16; bias concat ----
__global__ __launch_bounds__(256) void k_prep(
    const float* __restrict__ Wp, const float* __restrict__ We,
    const float* __restrict__ Wq, const float* __restrict__ Wk,
    const float* __restrict__ Wv, const float* __restrict__ Wo,
    const float* __restrict__ bp, const float* __restrict__ be,
    const float* __restrict__ bk, const float* __restrict__ bv,
    bf16_t* __restrict__ Wpe, bf16_t* __restrict__ Wqt,
    bf16_t* __restrict__ Wkv, bf16_t* __restrict__ Wot,
    float* __restrict__ bpe, float* __restrict__ bkv)
{
    int n = blockIdx.x, k = threadIdx.x;
    if (n < 512) {
        const float* S = (n < 256) ? Wp : We;
        int nn = n & 255;
        Wpe[n * 256 + k] = (bf16_t)S[k * 256 + nn];
    } else if (n < 768) {
        int nn = n - 512;
        Wqt[nn * 256 + k] = (bf16_t)Wq[k * 256 + nn];
    } else if (n < 1280) {
        int m2 = n - 768;
        const float* S = (m2 < 256) ? Wk : Wv;
        int nn = m2 & 255;
        Wkv[m2 * 256 + k] = (bf16_t)S[k * 256 + nn];
    } else if (n < 1536) {
        int nn = n - 1280;
        Wot[nn * 256 + k] = (bf16_t)Wo[k * 256 + nn];
    } else {
        bpe[k] = bp[k]; bpe[256 + k] = be[k];
        bkv[k] = bk[k]; bkv[256 + k] = bv[k];
    }
}

// ---- MFMA GEMM: [M x 256] fp32 A @ Wt[N x 256] bf16 ----
// mode 0: fp32 out + bias; mode 1: scatter-max (ntile0->pool, ntile1->emb);
// mode 2: bf16 out + bias.
__global__ __launch_bounds__(512, 2) void k_gemm(
    const float* __restrict__ A, int M,
    const bf16_t* __restrict__ Wt, const float* __restrict__ bias,
    int mode, float* __restrict__ outp, int ldo,
    const int* __restrict__ indices,
    unsigned* __restrict__ poolbits, unsigned* __restrict__ embbits)
{
    __shared__ __align__(16) bf16_t Abuf[128][72];
    __shared__ __align__(16) bf16_t Bbuf[256][72];
    __shared__ int sq_s[128], sk_s[128];

    const int t = threadIdx.x;
    const int wave = t >> 6, lane = t & 63;
    const int wr = wave >> 2, wc = wave & 3;
    const int lrow = lane & 15, quad = lane >> 4;
    const int row0 = blockIdx.y * 128;
    const int ntile = blockIdx.x;

    if (mode == 1 && t < 128) {
        int row = row0 + t;
        if (row < M) {
            const int* id = indices + (size_t)row * 4;
            int b = id[0], z = id[1], y = id[2], x = id[3];
            sq_s[t] = ((b * Zd + (z >> 3)) * Yd + (y >> 3)) * Xd + (x >> 3);
            sk_s[t] = ((b * Ze + (z / 40)) * Ye + (y / 15)) * Xe + (x >> 4);
        } else { sq_s[t] = 0; sk_s[t] = 0; }
    }

    f32x4 acc[4][4];
    #pragma unroll
    for (int mi = 0; mi < 4; ++mi)
        #pragma unroll
        for (int ni = 0; ni < 4; ++ni)
            acc[mi][ni] = (f32x4){0.f, 0.f, 0.f, 0.f};

    for (int k0 = 0; k0 < 256; k0 += 64) {
        #pragma unroll
        for (int i = 0; i < 4; ++i) {
            int c = i * 512 + t;
            int r = c >> 4, c4 = c & 15;
            float4 v = make_float4(0.f, 0.f, 0.f, 0.f);
            if (row0 + r < M)
                v = *(const float4*)(A + (size_t)(row0 + r) * 256 + k0 + c4 * 4);
            bf16x4 bv4;
            bv4[0] = (bf16_t)v.x; bv4[1] = (bf16_t)v.y;
            bv4[2] = (bf16_t)v.z; bv4[3] = (bf16_t)v.w;
            *(bf16x4*)&Abuf[r][c4 * 4] = bv4;
        }
        #pragma unroll
        for (int i = 0; i < 4; ++i) {
            int c = i * 512 + t;
            int r = c >> 3, c8 = c & 7;
            uint4 w = *(const uint4*)(Wt + ((size_t)(ntile * 256 + r)) * 256 + k0 + c8 * 8);
            *(uint4*)&Bbuf[r][c8 * 8] = w;
        }
        __syncthreads();

        #pragma unroll
        for (int kk = 0; kk < 64; kk += 32) {
            bf16x8 Af[4], Bf[4];
            #pragma unroll
            for (int mi = 0; mi < 4; ++mi)
                Af[mi] = *(const bf16x8*)&Abuf[wr * 64 + mi * 16 + lrow][kk + quad * 8];
            #pragma unroll
            for (int ni = 0; ni < 4; ++ni)
                Bf[ni] = *(const bf16x8*)&Bbuf[wc * 64 + ni * 16 + lrow][kk + quad * 8];
            #pragma unroll
            for (int mi = 0; mi < 4; ++mi)
                #pragma unroll
                for (int ni = 0; ni < 4; ++ni)
                    acc[mi][ni] = __builtin_amdgcn_mfma_f32_16x16x32_bf16(
                        Af[mi], Bf[ni], acc[mi][ni], 0, 0, 0);
        }
        __syncthreads();
    }

    const int colb = ntile * 256 + wc * 64;
    float biasv[4];
    #pragma unroll
    for (int ni = 0; ni < 4; ++ni) biasv[ni] = bias[colb + ni * 16 + lrow];

    if (mode == 0) {
        #pragma unroll
        for (int mi = 0; mi < 4; ++mi) {
            int lr = wr * 64 + mi * 16 + quad * 4;
            #pragma unroll
            for (int reg = 0; reg < 4; ++reg) {
                int grow = row0 + lr + reg;
                if (grow >= M) continue;
                #pragma unroll
                for (int ni = 0; ni < 4; ++ni) {
                    int col = colb + ni * 16 + lrow;
                    outp[(size_t)grow * ldo + col] = acc[mi][ni][reg] + biasv[ni];
                }
            }
        }
    } else if (mode == 2) {
        bf16_t* outb = (bf16_t*)outp;
        #pragma unroll
        for (int mi = 0; mi < 4; ++mi) {
            int lr = wr * 64 + mi * 16 + quad * 4;
            #pragma unroll
            for (int reg = 0; reg < 4; ++reg) {
                int grow = row0 + lr + reg;
                if (grow >= M) continue;
                #pragma unroll
                for (int ni = 0; ni < 4; ++ni) {
                    int col = colb + ni * 16 + lrow;
                    outb[(size_t)grow * ldo + col] = (bf16_t)(acc[mi][ni][reg] + biasv[ni]);
                }
            }
        }
    } else {
        #pragma unroll
        for (int mi = 0; mi < 4; ++mi) {
            int lr = wr * 64 + mi * 16 + quad * 4;
            #pragma unroll
            for (int reg = 0; reg < 4; ++reg) {
                int grow = row0 + lr + reg;
                if (grow >= M) continue;
                #pragma unroll
                for (int ni = 0; ni < 4; ++ni) {
                    int col = colb + ni * 16 + lrow;
                    float v = acc[mi][ni][reg] + biasv[ni];
                    if (col < 256)
                        atomicMax(&poolbits[(size_t)sq_s[lr + reg] * 256 + col], enc_f(v));
                    else
                        atomicMax(&embbits[(size_t)sk_s[lr + reg] * 256 + (col - 256)], enc_f(v));
                }
            }
        }
    }
}

// ---- sine PE helper ----
__device__ inline float pe_val(int j, float cz, float cy, float cx) {
    if (j >= 252) return 0.f;
    int dim = j / 84;
    int f = j % 84;
    int fi = (f >= 42) ? (f - 42) : f;
    float c  = (dim == 0) ? cz : ((dim == 1) ? cy : cx);
    float sp = (dim == 0) ? 480.f : ((dim == 1) ? 360.f : 32.f);
    float cn = c / sp * 6.28318530717958647692f;
    float tt = expf((float)fi * (9.210340371976184f / 42.f));
    float ang = cn / tt;
    return (f >= 42) ? cosf(ang) : sinf(ang);
}

__global__ __launch_bounds__(256) void k_pe_pool(
    const unsigned* __restrict__ bits, float* __restrict__ out)
{
    int s = blockIdx.x, j = threadIdx.x;
    unsigned m = bits[(size_t)s * D + j];
    float v = m ? dec_f(m) : 0.f;
    int rem = s % Gq;
    float cz = (float)((rem / (Yd * Xd)) * 8);
    float cy = (float)(((rem / Xd) % Yd) * 8);
    float cx = (float)((rem % Xd) * 8);
    out[(size_t)s * D + j] = v + pe_val(j, cz, cy, cx);
}

__global__ __launch_bounds__(256) void k_pe_emb(
    const unsigned* __restrict__ bits, float* __restrict__ out,
    int* __restrict__ kmask)
{
    int s = blockIdx.x, j = threadIdx.x;
    unsigned m = bits[(size_t)s * D + j];
    float v = m ? dec_f(m) : 0.f;
    int rem = s % Gk;
    float cz = (float)((rem / (Ye * Xe)) * 40);
    float cy = (float)(((rem / Xe) % Ye) * 15);
    float cx = (float)((rem % Xe) * 16);
    out[(size_t)s * D + j] = v + pe_val(j, cz, cy, cx);
    if (j == 0) kmask[s] = (bits[(size_t)s * D] != 0u) ? 1 : 0;
}

// ---- MFMA flash attention ----
// Q bf16 [Sq][256]; KV bf16 [Sk][512] (K at +0, V at +256); O fp32 [Sq][256].
// Block: 256 thr (4 waves); 64 Q-rows per block, one (b,h). Wave m-tile = 16 rows.
// Chunks of 192 keys; online softmax in C-layout regs; P via LDS to A-layout.
__global__ __launch_bounds__(256) void k_attn_mfma(
    const bf16_t* __restrict__ Q, const bf16_t* __restrict__ KV,
    const int* __restrict__ kmask, float* __restrict__ O)
{
    __shared__ __align__(16) bf16_t Qs[64][40];
    __shared__ __align__(16) bf16_t Ks[192][40];
    __shared__ __align__(16) bf16_t Vts[32][200];
    __shared__ __align__(16) bf16_t Ps[4][16][200];
    __shared__ float mskf[192];

    const int bh = blockIdx.y;
    const int b = bh >> 3, h = bh & 7;
    const int t = threadIdx.x, wave = t >> 6, lane = t & 63;
    const int lrow = lane & 15, quad = lane >> 4;
    const int q0 = blockIdx.x * 64;

    // stage Q tile (bf16 copy): 64 rows x 4 x 16B -> one uint4 per thread
    {
        int r = t >> 2, part = t & 3;
        int qi = q0 + r;
        uint4 val = make_uint4(0u, 0u, 0u, 0u);
        if (qi < Gq)
            val = *(const uint4*)(Q + ((size_t)(b * Gq + qi)) * 256 + h * 32 + part * 8);
        *(uint4*)&Qs[r][part * 8] = val;
    }
    __syncthreads();

    const bf16x8 Aq = *(const bf16x8*)&Qs[wave * 16 + lrow][quad * 8];

    f32x4 oacc[2];
    oacc[0] = (f32x4){0.f, 0.f, 0.f, 0.f};
    oacc[1] = (f32x4){0.f, 0.f, 0.f, 0.f};
    float m_run[4], l_run[4];
    #pragma unroll
    for (int r = 0; r < 4; ++r) { m_run[r] = -3.0e38f; l_run[r] = 0.f; }

    for (int c0 = 0; c0 < Gk; c0 += 192) {
        __syncthreads();
        // stage K chunk: 192 rows x 4 x 16B
        #pragma unroll
        for (int i = 0; i < 3; ++i) {
            int idx = i * 256 + t;
            int kk = idx >> 2, part = idx & 3;
            uint4 val = *(const uint4*)(KV + ((size_t)(b * Gk + c0 + kk)) * 512 + h * 32 + part * 8);
            *(uint4*)&Ks[kk][part * 8] = val;
        }
        // stage V chunk transposed: Vts[d][key]
        #pragma unroll
        for (int i = 0; i < 3; ++i) {
            int idx = i * 256 + t;
            int kk = idx >> 2, part = idx & 3;
            bf16x8 v = *(const bf16x8*)(KV + ((size_t)(b * Gk + c0 + kk)) * 512 + 256 + h * 32 + part * 8);
            #pragma unroll
            for (int j = 0; j < 8; ++j)
                Vts[part * 8 + j][kk] = v[j];
        }
        if (t < 192) mskf[t] = kmask[b * Gk + c0 + t] ? 0.f : -1.0e9f;
        __syncthreads();

        // QK^T: 12 n-tiles, single k-step (dh=32)
        float sreg[12][4];
        #pragma unroll
        for (int nt = 0; nt < 12; ++nt) {
            bf16x8 Bk = *(const bf16x8*)&Ks[nt * 16 + lrow][quad * 8];
            f32x4 sacc = __builtin_amdgcn_mfma_f32_16x16x32_bf16(
                Aq, Bk, (f32x4){0.f, 0.f, 0.f, 0.f}, 0, 0, 0);
            float pen = mskf[nt * 16 + lrow];
            #pragma unroll
            for (int r = 0; r < 4; ++r)
                sreg[nt][r] = sacc[r] * 0.17677669529663688f + pen;
        }

        // online softmax update (rows = quad*4+r; reduce over 16 lrow lanes)
        float alpha[4];
        #pragma unroll
        for (int r = 0; r < 4; ++r) {
            float mx = sreg[0][r];
            #pragma unroll
            for (int nt = 1; nt < 12; ++nt) mx = fmaxf(mx, sreg[nt][r]);
            #pragma unroll
            for (int off = 1; off < 16; off <<= 1)
                mx = fmaxf(mx, __shfl_xor(mx, off));
            float mnew = fmaxf(m_run[r], mx);
            alpha[r] = __expf(m_run[r] - mnew);
            m_run[r] = mnew;
            l_run[r] *= alpha[r];
        }
        #pragma unroll
        for (int n2 = 0; n2 < 2; ++n2)
            #pragma unroll
            for (int r = 0; r < 4; ++r) oacc[n2][r] *= alpha[r];

        float psum[4] = {0.f, 0.f, 0.f, 0.f};
        #pragma unroll
        for (int nt = 0; nt < 12; ++nt) {
            #pragma unroll
            for (int r = 0; r < 4; ++r) {
                float p = __expf(sreg[nt][r] - m_run[r]);
                psum[r] += p;
                Ps[wave][quad * 4 + r][nt * 16 + lrow] = (bf16_t)p;
            }
        }
        #pragma unroll
        for (int r = 0; r < 4; ++r) {
            float s = psum[r];
            #pragma unroll
            for (int off = 1; off < 16; off <<= 1) s += __shfl_xor(s, off);
            l_run[r] += s;
        }

        // PV: contraction over 192 keys = 6 k-steps, 2 n-tiles (dh=32)
        #pragma unroll
        for (int ks = 0; ks < 6; ++ks) {
            bf16x8 Ap = *(const bf16x8*)&Ps[wave][lrow][ks * 32 + quad * 8];
            #pragma unroll
            for (int n2 = 0; n2 < 2; ++n2) {
                bf16x8 Bv = *(const bf16x8*)&Vts[n2 * 16 + lrow][ks * 32 + quad * 8];
                oacc[n2] = __builtin_amdgcn_mfma_f32_16x16x32_bf16(
                    Ap, Bv, oacc[n2], 0, 0, 0);
            }
        }
    }

    #pragma unroll
    for (int r = 0; r < 4; ++r) {
        int qi = q0 + wave * 16 + quad * 4 + r;
        if (qi >= Gq) continue;
        float inv = (l_run[r] > 0.f) ? (1.f / l_run[r]) : 0.f;
        #pragma unroll
        for (int n2 = 0; n2 < 2; ++n2)
            O[((size_t)(b * Gq + qi)) * 256 + h * 32 + n2 * 16 + lrow] = oacc[n2][r] * inv;
    }
}

// ---- residual + LayerNorm ----
__global__ __launch_bounds__(256) void k_ln(
    const float* __restrict__ oproj, const float* __restrict__ resid,
    const float* __restrict__ g, const float* __restrict__ bta,
    float* __restrict__ out)
{
    const int s = blockIdx.x, t = threadIdx.x;
    float h = resid[(size_t)s * D + t] + oproj[(size_t)s * D + t];

    float s1 = h, s2 = h * h;
    for (int o = 32; o > 0; o >>= 1) {
        s1 += __shfl_down(s1, o);
        s2 += __shfl_down(s2, o);
    }
    __shared__ float r1[4], r2[4];
    __shared__ float mu_s, rstd_s;
    int w = t >> 6;
    if ((t & 63) == 0) { r1[w] = s1; r2[w] = s2; }
    __syncthreads();
    if (t == 0) {
        float a = r1[0] + r1[1] + r1[2] + r1[3];
        float bsum = r2[0] + r2[1] + r2[2] + r2[3];
        float mu = a * (1.f / 256.f);
        float var = bsum * (1.f / 256.f) - mu * mu;
        mu_s = mu;
        rstd_s = rsqrtf(var + 1e-5f);
    }
    __syncthreads();
    out[(size_t)s * D + t] = (h - mu_s) * rstd_s * g[t] + bta[t];
}

// ---- final: vox = feat + mhca[seg_q], logits = vox @ W_seg + b_seg ----
#define PTS 16
__global__ __launch_bounds__(320) void k_logits(
    const float* __restrict__ feat, const float* __restrict__ mhca,
    const int* __restrict__ indices, const float* __restrict__ Wseg,
    const float* __restrict__ bseg, float* __restrict__ out)
{
    __shared__ float vox[PTS][D + 1];
    __shared__ float Wl[D * OUTC];
    __shared__ int sq[PTS];
    const int t = threadIdx.x;
    const int p0 = blockIdx.x * PTS;

    if (t < PTS) {
        const int* id = indices + (size_t)(p0 + t) * 4;
        sq[t] = ((id[0] * Zd + (id[1] >> 3)) * Yd + (id[2] >> 3)) * Xd + (id[3] >> 3);
    }
    for (int idx = t; idx < D * OUTC; idx += 320) Wl[idx] = Wseg[idx];
    __syncthreads();
    for (int idx = t; idx < PTS * D; idx += 320) {
        int r = idx / D, k = idx % D;
        vox[r][k] = feat[(size_t)(p0 + r) * D + k] + mhca[(size_t)sq[r] * D + k];
    }
    __syncthreads();

    const int r = t / OUTC, o = t % OUTC;
    float acc = bseg[o];
    #pragma unroll 4
    for (int k = 0; k < D; ++k) acc += vox[r][k] * Wl[k * OUTC + o];
    out[(size_t)(p0 + r) * OUTC + o] = acc;
}

extern "C" void kernel_launch(void* const* d_in, const int* in_sizes, int n_in,
                              void* d_out, int out_size, void* d_ws, size_t ws_size,
                              hipStream_t stream) {
    const float* features = (const float*)d_in[0];
    const float* W_pool = (const float*)d_in[1];
    const float* b_pool = (const float*)d_in[2];
    const float* W_emb  = (const float*)d_in[3];
    const float* b_emb  = (const float*)d_in[4];
    const float* Wq = (const float*)d_in[5];
    const float* bq = (const float*)d_in[6];
    const float* Wk = (const float*)d_in[7];
    const float* bk = (const float*)d_in[8];
    const float* Wv = (const float*)d_in[9];
    const float* bv = (const float*)d_in[10];
    const float* Wo = (const float*)d_in[11];
    const float* bo = (const float*)d_in[12];
    const float* ln_g = (const float*)d_in[13];
    const float* ln_b = (const float*)d_in[14];
    const float* W_seg = (const float*)d_in[15];
    const float* b_seg = (const float*)d_in[16];
    const int* indices = (const int*)d_in[17];
    float* out = (float*)d_out;

    float* ws = (float*)d_ws;
    const size_t SQD = (size_t)Sq * D;   // 5,529,600
    const size_t SKD = (size_t)Sk * D;   // 294,912
    // ALL offsets in float (4-byte) units.
    size_t o0 = 0;               // poolbits -> attnO -> mhca
    size_t o1 = o0 + SQD;        // embbits
    size_t o2 = o1 + SKD;        // pool_feat
    size_t o3 = o2 + SQD;        // emb_feat
    size_t o4 = o3 + SKD;        // Qb (bf16) -> oproj (fp32)
    size_t o5 = o4 + SQD;        // KVb (bf16 [Sk][512], uses half the slot)
    size_t o6 = o5 + 2 * SKD;    // kmask (1152 ints)
    size_t o7 = o6 + 2048;       // Wpe bf16 [512][256] = 65536 floats
    size_t o8 = o7 + 65536;      // Wqt bf16 [256][256] = 32768 floats
    size_t o9 = o8 + 32768;      // Wkv bf16 [512][256] = 65536 floats
    size_t o10 = o9 + 65536;     // Wot bf16 [256][256] = 32768 floats
    size_t o11 = o10 + 32768;    // bias pe [512]
    size_t o12 = o11 + 512;      // bias kv [512]

    unsigned* poolbits = (unsigned*)(ws + o0);
    unsigned* embbits  = (unsigned*)(ws + o1);
    float* pool_feat = ws + o2;
    float* emb_feat  = ws + o3;
    bf16_t* Qb  = (bf16_t*)(ws + o4);
    bf16_t* KVb = (bf16_t*)(ws + o5);
    int* kmask = (int*)(ws + o6);
    bf16_t* Wpe = (bf16_t*)(ws + o7);
    bf16_t* Wqt = (bf16_t*)(ws + o8);
    bf16_t* Wkv = (bf16_t*)(ws + o9);
    bf16_t* Wot = (bf16_t*)(ws + o10);
    float* bpe = ws + o11;
    float* bkv = ws + o12;
    float* attnO = ws + o0;
    float* oproj = ws + o4;
    float* mhca  = ws + o0;

    hipMemsetAsync(d_ws, 0, (SQD + SKD) * sizeof(unsigned), stream);

    k_prep<<<1537, 256, 0, stream>>>(W_pool, W_emb, Wq, Wk, Wv, Wo,
                                     b_pool, b_emb, bk, bv,
                                     Wpe, Wqt, Wkv, Wot, bpe, bkv);

    // dual linear + scatter-max: [120000x256] @ Wpe^T[512x256]
    {
        dim3 g(2, (N_PTS + 127) / 128);
        k_gemm<<<g, 512, 0, stream>>>(features, N_PTS, Wpe, bpe, 1,
                                      nullptr, 0, indices, poolbits, embbits);
    }

    k_pe_pool<<<Sq, 256, 0, stream>>>(poolbits, pool_feat);
    k_pe_emb<<<Sk, 256, 0, stream>>>(embbits, emb_feat, kmask);

    // Q = pool_feat @ Wq + bq  (bf16 out)
    {
        dim3 g(1, (Sq + 127) / 128);
        k_gemm<<<g, 512, 0, stream>>>(pool_feat, Sq, Wqt, bq, 2,
                                      (float*)Qb, 256, nullptr, nullptr, nullptr);
    }
    // KV = emb_feat @ [Wk|Wv] + [bk|bv], interleaved bf16 [Sk][512]
    {
        dim3 g(2, (Sk + 127) / 128);
        k_gemm<<<g, 512, 0, stream>>>(emb_feat, Sk, Wkv, bkv, 2,
                                      (float*)KVb, 512, nullptr, nullptr, nullptr);
    }

    {
        dim3 ag((Gq + 63) / 64, BATCH * NH);
        k_attn_mfma<<<ag, 256, 0, stream>>>(Qb, KVb, kmask, attnO);
    }

    // oproj = attnO @ Wo + bo (fp32 out)
    {
        dim3 g(1, (Sq + 127) / 128);
        k_gemm<<<g, 512, 0, stream>>>(attnO, Sq, Wot, bo, 0,
                                      oproj, 256, nullptr, nullptr, nullptr);
    }

    k_ln<<<Sq, 256, 0, stream>>>(oproj, pool_feat, ln_g, ln_b, mhca);

    k_logits<<<N_PTS / PTS, 320, 0, stream>>>(
        features, mhca, indices, W_seg, b_seg, out);
}